// Round 1
// baseline (2225.535 us; speedup 1.0000x reference)
//
#include <hip/hip_runtime.h>
#include <hip/hip_bf16.h>

#define DD 128
#define AA 5

// ---------------- node precompute: node_x, p1, p2 ----------------
// one wave (64 lanes) per node; lane holds 2 feature elements.
__global__ __launch_bounds__(256) void k_node_pre(
    const float* __restrict__ x, const float* __restrict__ naw, const float* __restrict__ nab,
    const float* __restrict__ nanchor, const float* __restrict__ eww,
    float* __restrict__ node_x, float* __restrict__ p1, float* __restrict__ p2, int N)
{
    int wave = threadIdx.x >> 6;
    int lane = threadIdx.x & 63;
    int u = blockIdx.x * 4 + wave;
    if (u >= N) return;
    int d0 = lane * 2;
    float2 xv = *(const float2*)(x + (size_t)u * DD + d0);
    float nl[AA], a1[AA], a2[AA];
#pragma unroll
    for (int a = 0; a < AA; a++) {
        nl[a] = xv.x * naw[d0 * AA + a] + xv.y * naw[(d0 + 1) * AA + a];
        a1[a] = xv.x * eww[d0 * AA + a] + xv.y * eww[(d0 + 1) * AA + a];
        a2[a] = xv.x * eww[(DD + d0) * AA + a] + xv.y * eww[(DD + d0 + 1) * AA + a];
    }
#pragma unroll
    for (int off = 32; off >= 1; off >>= 1) {
#pragma unroll
        for (int a = 0; a < AA; a++) {
            nl[a] += __shfl_xor(nl[a], off, 64);
            a1[a] += __shfl_xor(a1[a], off, 64);
            a2[a] += __shfl_xor(a2[a], off, 64);
        }
    }
    // softmax(nl + bias) over A=5 (all lanes redundantly)
    float m = -1e30f;
#pragma unroll
    for (int a = 0; a < AA; a++) { nl[a] += nab[a]; m = fmaxf(m, nl[a]); }
    float ssum = 0.f;
#pragma unroll
    for (int a = 0; a < AA; a++) { nl[a] = __expf(nl[a] - m); ssum += nl[a]; }
    float inv = 1.0f / ssum;
    float2 o = xv;
#pragma unroll
    for (int a = 0; a < AA; a++) {
        float wgt = nl[a] * inv;
        o.x += wgt * nanchor[a * DD + d0];
        o.y += wgt * nanchor[a * DD + d0 + 1];
    }
    *(float2*)(node_x + (size_t)u * DD + d0) = o;
    if (lane == 0) {
#pragma unroll
        for (int a = 0; a < AA; a++) { p1[u * 8 + a] = a1[a]; p2[u * 8 + a] = a2[a]; }
    }
}

// ---------------- edge kernel: b coeffs, edge_prompt out, coef scatter ----------------
__global__ __launch_bounds__(256) void k_edge(
    const int* __restrict__ ei, const float* __restrict__ p1, const float* __restrict__ p2,
    const float* __restrict__ ewb, const float* __restrict__ eanchor,
    float* __restrict__ eprompt, float* __restrict__ coef, int E)
{
    __shared__ float be_sh[256][6];
    __shared__ float anc[AA][DD];
    int tid = threadIdx.x;
    for (int i = tid; i < AA * DD; i += 256) anc[i / DD][i % DD] = eanchor[i];
    int e0 = blockIdx.x * 256;
    int e = e0 + tid;
    if (e < E) {
        int s = ei[e], d = ei[E + e];
        float l[AA];
        float4 q1 = *(const float4*)(p1 + (size_t)s * 8);
        float  q1e = p1[(size_t)s * 8 + 4];
        float4 q2 = *(const float4*)(p2 + (size_t)d * 8);
        float  q2e = p2[(size_t)d * 8 + 4];
        l[0] = q1.x + q2.x; l[1] = q1.y + q2.y; l[2] = q1.z + q2.z; l[3] = q1.w + q2.w; l[4] = q1e + q2e;
        float m = -1e30f;
#pragma unroll
        for (int a = 0; a < AA; a++) {
            l[a] += ewb[a];
            l[a] = l[a] >= 0.f ? l[a] : 0.01f * l[a];  // leaky_relu
            m = fmaxf(m, l[a]);
        }
        float ssum = 0.f;
#pragma unroll
        for (int a = 0; a < AA; a++) { l[a] = __expf(l[a] - m); ssum += l[a]; }
        float inv = 1.f / ssum;
#pragma unroll
        for (int a = 0; a < AA; a++) {
            float b = l[a] * inv;
            be_sh[tid][a] = b;
            atomicAdd(&coef[(size_t)s * 8 + a], b);
            atomicAdd(&coef[(size_t)d * 8 + a], b);
        }
    }
    __syncthreads();
    // phase 2: cooperative coalesced write of edge_prompt rows
    int c4 = tid & 31;
    int r  = tid >> 5;
    int nvalid = min(256, E - e0);
    for (int j = r; j < nvalid; j += 8) {
        float4 v = {0.f, 0.f, 0.f, 0.f};
#pragma unroll
        for (int a = 0; a < AA; a++) {
            float b = be_sh[j][a];
            v.x += b * anc[a][c4 * 4 + 0];
            v.y += b * anc[a][c4 * 4 + 1];
            v.z += b * anc[a][c4 * 4 + 2];
            v.w += b * anc[a][c4 * 4 + 3];
        }
        *(float4*)(eprompt + (size_t)(e0 + j) * DD + c4 * 4) = v;
    }
}

// ---------------- z = node_x + coef @ edge_anchor (in-place) ----------------
__global__ __launch_bounds__(256) void k_z(
    const float* __restrict__ coef, const float* __restrict__ eanchor,
    float* __restrict__ z, int N)
{
    int idx = blockIdx.x * 256 + threadIdx.x;
    int u = idx >> 5, c4 = idx & 31;
    if (u >= N) return;
    float c[AA];
#pragma unroll
    for (int a = 0; a < AA; a++) c[a] = coef[(size_t)u * 8 + a];
    float4 v = *(float4*)(z + (size_t)u * DD + c4 * 4);
#pragma unroll
    for (int a = 0; a < AA; a++) {
        const float4 an = *(const float4*)(eanchor + a * DD + c4 * 4);
        v.x += c[a] * an.x; v.y += c[a] * an.y; v.z += c[a] * an.z; v.w += c[a] * an.w;
    }
    *(float4*)(z + (size_t)u * DD + c4 * 4) = v;
}

// ---------------- CSR build ----------------
__global__ __launch_bounds__(256) void k_deg(const int* __restrict__ ei, int* __restrict__ deg, int E)
{
    int e = blockIdx.x * 256 + threadIdx.x;
    if (e >= E) return;
    atomicAdd(&deg[ei[e]], 1);
    atomicAdd(&deg[ei[E + e]], 1);
}

__global__ __launch_bounds__(1024) void k_scan(
    const int* __restrict__ deg, int* __restrict__ rowptr, int* __restrict__ wp, int N, int total)
{
    __shared__ int sdata[1024];
    int t = threadIdx.x;
    int chunk = (N + 1023) >> 10;
    int start = t * chunk, end = min(start + chunk, N);
    int lsum = 0;
    for (int i = start; i < end; i++) lsum += deg[i];
    sdata[t] = lsum;
    __syncthreads();
    for (int off = 1; off < 1024; off <<= 1) {
        int v = (t >= off) ? sdata[t - off] : 0;
        __syncthreads();
        sdata[t] += v;
        __syncthreads();
    }
    int run = sdata[t] - lsum;  // exclusive prefix
    for (int i = start; i < end; i++) { rowptr[i] = run; wp[i] = run; run += deg[i]; }
    if (t == 0) rowptr[N] = total;
}

__global__ __launch_bounds__(256) void k_fill(
    const int* __restrict__ ei, int* __restrict__ wp, int* __restrict__ adj, int E)
{
    int e = blockIdx.x * 256 + threadIdx.x;
    if (e >= E) return;
    int s = ei[e], d = ei[E + e];
    int ps = atomicAdd(&wp[s], 1); adj[ps] = d;
    int pd = atomicAdd(&wp[d], 1); adj[pd] = s;
}

// ---------------- one wavelet step: yout = 0.5*yin + (0.5/norm)*Adj*yin ----------------
// 32 lanes per node (float4 per lane), 4 nodes per 128-thread block
__global__ __launch_bounds__(128) void k_wav(
    const int* __restrict__ rowptr, const int* __restrict__ adj,
    const float* __restrict__ yin, int in_stride,
    float* __restrict__ yout, int out_stride,
    float halfinvnorm, int N)
{
    int nl = threadIdx.x >> 5;
    int c4 = threadIdx.x & 31;
    int u = blockIdx.x * 4 + nl;
    if (u >= N) return;
    int beg = rowptr[u], end = rowptr[u + 1];
    float4 sum = {0.f, 0.f, 0.f, 0.f};
    for (int j = beg; j < end; j++) {
        int nb = adj[j];
        const float4 v = *(const float4*)(yin + (size_t)nb * in_stride + c4 * 4);
        sum.x += v.x; sum.y += v.y; sum.z += v.z; sum.w += v.w;
    }
    const float4 self = *(const float4*)(yin + (size_t)u * in_stride + c4 * 4);
    float4 o;
    o.x = 0.5f * self.x + halfinvnorm * sum.x;
    o.y = 0.5f * self.y + halfinvnorm * sum.y;
    o.z = 0.5f * self.z + halfinvnorm * sum.z;
    o.w = 0.5f * self.w + halfinvnorm * sum.w;
    *(float4*)(yout + (size_t)u * out_stride + c4 * 4) = o;
}

// ---------------- MLP stage 1: h = relu(comb_scaled @ w1 + b1), scales folded into w1 ----------------
__global__ __launch_bounds__(256) void k_mlp1(
    const float* __restrict__ comb, const float* __restrict__ w1,
    const float* __restrict__ b1, const float* __restrict__ scales,
    float* __restrict__ h, int N)
{
    __shared__ float w1s[32][256];
    __shared__ float cs[32][33];
    int tid = threadIdx.x;
    int r0 = blockIdx.x * 32;
    float acc[32];
#pragma unroll
    for (int r = 0; r < 32; r++) acc[r] = 0.f;
    float sc[4] = {scales[0], scales[1], scales[2], scales[3]};
    for (int k0 = 0; k0 < 512; k0 += 32) {
#pragma unroll 4
        for (int kk = 0; kk < 32; kk++)
            w1s[kk][tid] = w1[(size_t)(k0 + kk) * 256 + tid] * sc[(k0 + kk) >> 7];
#pragma unroll
        for (int i = 0; i < 4; i++) {
            int idx = tid + i * 256;
            int r = idx >> 5, kk = idx & 31;
            int row = r0 + r;
            cs[r][kk] = (row < N) ? comb[(size_t)row * 512 + k0 + kk] : 0.f;
        }
        __syncthreads();
#pragma unroll 8
        for (int kk = 0; kk < 32; kk++) {
            float wv = w1s[kk][tid];
#pragma unroll
            for (int r = 0; r < 32; r++) acc[r] += cs[r][kk] * wv;
        }
        __syncthreads();
    }
    float bb = b1[tid];
    for (int r = 0; r < 32; r++) {
        int row = r0 + r;
        if (row < N) h[(size_t)row * 256 + tid] = fmaxf(acc[r] + bb, 0.f);
    }
}

// ---------------- MLP stage 2: final = h @ w2 + b2 ----------------
__global__ __launch_bounds__(128) void k_mlp2(
    const float* __restrict__ h, const float* __restrict__ w2,
    const float* __restrict__ b2, float* __restrict__ out, int N)
{
    __shared__ float w2s[32][128];
    __shared__ float hs[32][33];
    int tid = threadIdx.x;
    int r0 = blockIdx.x * 32;
    float acc[32];
#pragma unroll
    for (int r = 0; r < 32; r++) acc[r] = 0.f;
    for (int k0 = 0; k0 < 256; k0 += 32) {
#pragma unroll 4
        for (int kk = 0; kk < 32; kk++)
            w2s[kk][tid] = w2[(size_t)(k0 + kk) * 128 + tid];
#pragma unroll
        for (int i = 0; i < 8; i++) {
            int idx = tid + i * 128;
            int r = idx >> 5, kk = idx & 31;
            int row = r0 + r;
            hs[r][kk] = (row < N) ? h[(size_t)row * 256 + k0 + kk] : 0.f;
        }
        __syncthreads();
#pragma unroll 8
        for (int kk = 0; kk < 32; kk++) {
            float wv = w2s[kk][tid];
#pragma unroll
            for (int r = 0; r < 32; r++) acc[r] += hs[r][kk] * wv;
        }
        __syncthreads();
    }
    float bb = b2[tid];
    for (int r = 0; r < 32; r++) {
        int row = r0 + r;
        if (row < N) out[(size_t)row * 128 + tid] = acc[r] + bb;
    }
}

extern "C" void kernel_launch(void* const* d_in, const int* in_sizes, int n_in,
                              void* d_out, int out_size, void* d_ws, size_t ws_size,
                              hipStream_t stream)
{
    const float* x       = (const float*)d_in[0];
    const int*   ei      = (const int*)d_in[1];
    const float* nanchor = (const float*)d_in[2];
    const float* naw     = (const float*)d_in[3];
    const float* nab     = (const float*)d_in[4];
    const float* eanchor = (const float*)d_in[5];
    const float* eww     = (const float*)d_in[6];
    const float* ewb     = (const float*)d_in[7];
    const float* scales  = (const float*)d_in[8];
    const float* w1      = (const float*)d_in[9];
    const float* b1      = (const float*)d_in[10];
    const float* w2      = (const float*)d_in[11];
    const float* b2      = (const float*)d_in[12];

    int N = in_sizes[0] / DD;
    int E = in_sizes[1] / 2;
    float norm = (float)((double)E / (double)N + 1e-6);
    float hin = 0.5f / norm;

    char* wsb = (char*)d_ws;
    size_t off = 0;
    auto alloc = [&](size_t b) -> char* {
        char* p = wsb + off;
        off += (b + 255) & ~(size_t)255;
        return p;
    };
    float* node_x = (float*)alloc((size_t)N * DD * 4);   // becomes z after k_z
    float* p1     = (float*)alloc((size_t)N * 8 * 4);
    float* p2     = (float*)alloc((size_t)N * 8 * 4);
    float* coef   = (float*)alloc((size_t)N * 8 * 4);
    float* comb   = (float*)alloc((size_t)N * 512 * 4);  // y1..y4 chunks
    float* hbuf   = (float*)alloc((size_t)N * 256 * 4);
    int*   deg    = (int*)alloc((size_t)N * 4);
    int*   rowptr = (int*)alloc((size_t)(N + 1) * 4);
    int*   wp     = (int*)alloc((size_t)N * 4);
    int*   adj    = (int*)alloc((size_t)2 * E * 4);

    float* out_final   = (float*)d_out;
    float* out_eprompt = out_final + (size_t)N * DD;

    hipMemsetAsync(coef, 0, (size_t)N * 8 * 4, stream);
    hipMemsetAsync(deg, 0, (size_t)N * 4, stream);

    k_node_pre<<<(N + 3) / 4, 256, 0, stream>>>(x, naw, nab, nanchor, eww, node_x, p1, p2, N);
    k_edge<<<(E + 255) / 256, 256, 0, stream>>>(ei, p1, p2, ewb, eanchor, out_eprompt, coef, E);
    k_deg<<<(E + 255) / 256, 256, 0, stream>>>(ei, deg, E);
    k_scan<<<1, 1024, 0, stream>>>(deg, rowptr, wp, N, 2 * E);
    k_fill<<<(E + 255) / 256, 256, 0, stream>>>(ei, wp, adj, E);
    k_z<<<((size_t)N * 32 + 255) / 256, 256, 0, stream>>>(coef, eanchor, node_x, N);

    // 4 chained wavelet steps: comb chunk s holds y_{s+1} (unscaled; scales folded into MLP1)
    k_wav<<<(N + 3) / 4, 128, 0, stream>>>(rowptr, adj, node_x, DD, comb + 0, 512, hin, N);
    k_wav<<<(N + 3) / 4, 128, 0, stream>>>(rowptr, adj, comb + 0, 512, comb + 128, 512, hin, N);
    k_wav<<<(N + 3) / 4, 128, 0, stream>>>(rowptr, adj, comb + 128, 512, comb + 256, 512, hin, N);
    k_wav<<<(N + 3) / 4, 128, 0, stream>>>(rowptr, adj, comb + 256, 512, comb + 384, 512, hin, N);

    k_mlp1<<<(N + 31) / 32, 256, 0, stream>>>(comb, w1, b1, scales, hbuf, N);
    k_mlp2<<<(N + 31) / 32, 128, 0, stream>>>(hbuf, w2, b2, out_final, N);
}

// Round 2
// 1413.465 us; speedup vs baseline: 1.5745x; 1.5745x over previous
//
#include <hip/hip_runtime.h>
#include <hip/hip_bf16.h>

#define DD 128
#define AA 5

typedef short short8 __attribute__((ext_vector_type(8)));
typedef float f32x4 __attribute__((ext_vector_type(4)));

static __device__ __forceinline__ unsigned short f2bf(float f) {
    union { float f; unsigned u; } v; v.f = f;
    unsigned r = (v.u + 0x7fff + ((v.u >> 16) & 1)) >> 16;
    return (unsigned short)r;
}

// ---------------- node precompute: node_x, p1, p2 ----------------
__global__ __launch_bounds__(256) void k_node_pre(
    const float* __restrict__ x, const float* __restrict__ naw, const float* __restrict__ nab,
    const float* __restrict__ nanchor, const float* __restrict__ eww,
    float* __restrict__ node_x, float* __restrict__ p1, float* __restrict__ p2, int N)
{
    int wave = threadIdx.x >> 6;
    int lane = threadIdx.x & 63;
    int u = blockIdx.x * 4 + wave;
    if (u >= N) return;
    int d0 = lane * 2;
    float2 xv = *(const float2*)(x + (size_t)u * DD + d0);
    float nl[AA], a1[AA], a2[AA];
#pragma unroll
    for (int a = 0; a < AA; a++) {
        nl[a] = xv.x * naw[d0 * AA + a] + xv.y * naw[(d0 + 1) * AA + a];
        a1[a] = xv.x * eww[d0 * AA + a] + xv.y * eww[(d0 + 1) * AA + a];
        a2[a] = xv.x * eww[(DD + d0) * AA + a] + xv.y * eww[(DD + d0 + 1) * AA + a];
    }
#pragma unroll
    for (int off = 32; off >= 1; off >>= 1) {
#pragma unroll
        for (int a = 0; a < AA; a++) {
            nl[a] += __shfl_xor(nl[a], off, 64);
            a1[a] += __shfl_xor(a1[a], off, 64);
            a2[a] += __shfl_xor(a2[a], off, 64);
        }
    }
    float m = -1e30f;
#pragma unroll
    for (int a = 0; a < AA; a++) { nl[a] += nab[a]; m = fmaxf(m, nl[a]); }
    float ssum = 0.f;
#pragma unroll
    for (int a = 0; a < AA; a++) { nl[a] = __expf(nl[a] - m); ssum += nl[a]; }
    float inv = 1.0f / ssum;
    float2 o = xv;
#pragma unroll
    for (int a = 0; a < AA; a++) {
        float wgt = nl[a] * inv;
        o.x += wgt * nanchor[a * DD + d0];
        o.y += wgt * nanchor[a * DD + d0 + 1];
    }
    *(float2*)(node_x + (size_t)u * DD + d0) = o;
    if (lane == 0) {
#pragma unroll
        for (int a = 0; a < AA; a++) { p1[u * 8 + a] = a1[a]; p2[u * 8 + a] = a2[a]; }
    }
}

// ---------------- edge kernel ----------------
__global__ __launch_bounds__(256) void k_edge(
    const int* __restrict__ ei, const float* __restrict__ p1, const float* __restrict__ p2,
    const float* __restrict__ ewb, const float* __restrict__ eanchor,
    float* __restrict__ eprompt, float* __restrict__ coef, int E)
{
    __shared__ float be_sh[256][6];
    __shared__ float anc[AA][DD];
    int tid = threadIdx.x;
    for (int i = tid; i < AA * DD; i += 256) anc[i / DD][i % DD] = eanchor[i];
    int e0 = blockIdx.x * 256;
    int e = e0 + tid;
    if (e < E) {
        int s = ei[e], d = ei[E + e];
        float l[AA];
        float4 q1 = *(const float4*)(p1 + (size_t)s * 8);
        float  q1e = p1[(size_t)s * 8 + 4];
        float4 q2 = *(const float4*)(p2 + (size_t)d * 8);
        float  q2e = p2[(size_t)d * 8 + 4];
        l[0] = q1.x + q2.x; l[1] = q1.y + q2.y; l[2] = q1.z + q2.z; l[3] = q1.w + q2.w; l[4] = q1e + q2e;
        float m = -1e30f;
#pragma unroll
        for (int a = 0; a < AA; a++) {
            l[a] += ewb[a];
            l[a] = l[a] >= 0.f ? l[a] : 0.01f * l[a];
            m = fmaxf(m, l[a]);
        }
        float ssum = 0.f;
#pragma unroll
        for (int a = 0; a < AA; a++) { l[a] = __expf(l[a] - m); ssum += l[a]; }
        float inv = 1.f / ssum;
#pragma unroll
        for (int a = 0; a < AA; a++) {
            float b = l[a] * inv;
            be_sh[tid][a] = b;
            atomicAdd(&coef[(size_t)s * 8 + a], b);
            atomicAdd(&coef[(size_t)d * 8 + a], b);
        }
    }
    __syncthreads();
    int c4 = tid & 31;
    int r  = tid >> 5;
    int nvalid = min(256, E - e0);
    for (int j = r; j < nvalid; j += 8) {
        float4 v = {0.f, 0.f, 0.f, 0.f};
#pragma unroll
        for (int a = 0; a < AA; a++) {
            float b = be_sh[j][a];
            v.x += b * anc[a][c4 * 4 + 0];
            v.y += b * anc[a][c4 * 4 + 1];
            v.z += b * anc[a][c4 * 4 + 2];
            v.w += b * anc[a][c4 * 4 + 3];
        }
        *(float4*)(eprompt + (size_t)(e0 + j) * DD + c4 * 4) = v;
    }
}

// ---------------- z = node_x + coef @ edge_anchor (in-place) ----------------
__global__ __launch_bounds__(256) void k_z(
    const float* __restrict__ coef, const float* __restrict__ eanchor,
    float* __restrict__ z, int N)
{
    int idx = blockIdx.x * 256 + threadIdx.x;
    int u = idx >> 5, c4 = idx & 31;
    if (u >= N) return;
    float c[AA];
#pragma unroll
    for (int a = 0; a < AA; a++) c[a] = coef[(size_t)u * 8 + a];
    float4 v = *(float4*)(z + (size_t)u * DD + c4 * 4);
#pragma unroll
    for (int a = 0; a < AA; a++) {
        const float4 an = *(const float4*)(eanchor + a * DD + c4 * 4);
        v.x += c[a] * an.x; v.y += c[a] * an.y; v.z += c[a] * an.z; v.w += c[a] * an.w;
    }
    *(float4*)(z + (size_t)u * DD + c4 * 4) = v;
}

// ---------------- CSR build ----------------
__global__ __launch_bounds__(256) void k_deg(const int* __restrict__ ei, int* __restrict__ deg, int E)
{
    int e = blockIdx.x * 256 + threadIdx.x;
    if (e >= E) return;
    atomicAdd(&deg[ei[e]], 1);
    atomicAdd(&deg[ei[E + e]], 1);
}

__global__ __launch_bounds__(1024) void k_scan(
    const int* __restrict__ deg, int* __restrict__ rowptr, int* __restrict__ wp, int N, int total)
{
    __shared__ int sdata[1024];
    int t = threadIdx.x;
    int chunk = (N + 1023) >> 10;
    int start = t * chunk, end = min(start + chunk, N);
    int lsum = 0;
    for (int i = start; i < end; i++) lsum += deg[i];
    sdata[t] = lsum;
    __syncthreads();
    for (int off = 1; off < 1024; off <<= 1) {
        int v = (t >= off) ? sdata[t - off] : 0;
        __syncthreads();
        sdata[t] += v;
        __syncthreads();
    }
    int run = sdata[t] - lsum;
    for (int i = start; i < end; i++) { rowptr[i] = run; wp[i] = run; run += deg[i]; }
    if (t == 0) rowptr[N] = total;
}

__global__ __launch_bounds__(256) void k_fill(
    const int* __restrict__ ei, int* __restrict__ wp, int* __restrict__ adj, int E)
{
    int e = blockIdx.x * 256 + threadIdx.x;
    if (e >= E) return;
    int s = ei[e], d = ei[E + e];
    int ps = atomicAdd(&wp[s], 1); adj[ps] = d;
    int pd = atomicAdd(&wp[d], 1); adj[pd] = s;
}

// ---------------- wavelet step: fp32 out (optional) + bf16 mirror ----------------
__global__ __launch_bounds__(128) void k_wav(
    const int* __restrict__ rowptr, const int* __restrict__ adj,
    const float* __restrict__ yin, int in_stride,
    float* __restrict__ yout, int write_f32,
    unsigned short* __restrict__ bfout,   // comb_bf16 + chunk, stride 512
    float halfinvnorm, int N)
{
    int nl = threadIdx.x >> 5;
    int c4 = threadIdx.x & 31;
    int u = blockIdx.x * 4 + nl;
    if (u >= N) return;
    int beg = rowptr[u], end = rowptr[u + 1];
    float4 s0 = {0.f, 0.f, 0.f, 0.f}, s1 = {0.f, 0.f, 0.f, 0.f};
    int j = beg;
    for (; j + 1 < end; j += 2) {
        int n0 = adj[j], n1 = adj[j + 1];
        const float4 v0 = *(const float4*)(yin + (size_t)n0 * in_stride + c4 * 4);
        const float4 v1 = *(const float4*)(yin + (size_t)n1 * in_stride + c4 * 4);
        s0.x += v0.x; s0.y += v0.y; s0.z += v0.z; s0.w += v0.w;
        s1.x += v1.x; s1.y += v1.y; s1.z += v1.z; s1.w += v1.w;
    }
    if (j < end) {
        int n0 = adj[j];
        const float4 v0 = *(const float4*)(yin + (size_t)n0 * in_stride + c4 * 4);
        s0.x += v0.x; s0.y += v0.y; s0.z += v0.z; s0.w += v0.w;
    }
    const float4 self = *(const float4*)(yin + (size_t)u * in_stride + c4 * 4);
    float4 o;
    o.x = 0.5f * self.x + halfinvnorm * (s0.x + s1.x);
    o.y = 0.5f * self.y + halfinvnorm * (s0.y + s1.y);
    o.z = 0.5f * self.z + halfinvnorm * (s0.z + s1.z);
    o.w = 0.5f * self.w + halfinvnorm * (s0.w + s1.w);
    if (write_f32)
        *(float4*)(yout + (size_t)u * DD + c4 * 4) = o;
    ushort4 b;
    b.x = f2bf(o.x); b.y = f2bf(o.y); b.z = f2bf(o.z); b.w = f2bf(o.w);
    *(ushort4*)(bfout + (size_t)u * 512 + c4 * 4) = b;
}

// ---------------- weight conversion (transposed, bf16) ----------------
__global__ __launch_bounds__(256) void k_cvtw1(
    const float* __restrict__ w1, const float* __restrict__ scales,
    unsigned short* __restrict__ w1t)
{
    int t = blockIdx.x * 256 + threadIdx.x;
    if (t >= 512 * 256) return;
    int k = t >> 8, n = t & 255;
    w1t[n * 512 + k] = f2bf(w1[t] * scales[k >> 7]);
}

__global__ __launch_bounds__(256) void k_cvtw2(
    const float* __restrict__ w2, unsigned short* __restrict__ w2t)
{
    int t = blockIdx.x * 256 + threadIdx.x;
    if (t >= 256 * 128) return;
    int k = t >> 7, n = t & 127;
    w2t[n * 256 + k] = f2bf(w2[t]);
}

// ---------------- MFMA GEMM: out[N,NOUT] = A[N,K] @ Bt[NOUT,K]^T + bias ----------------
// block: 256 thr = 4 waves; tile M=128, N=64, BK=32; wave = 32 rows x 64 cols.
// RELU_BF16: relu + bf16 out (mlp1 -> h); else fp32 out (mlp2 -> d_out).
template<int K, bool RELU_BF16>
__global__ __launch_bounds__(256) void k_gemm(
    const unsigned short* __restrict__ A, const unsigned short* __restrict__ Bt,
    const float* __restrict__ bias, void* __restrict__ outp, int N, int NOUT)
{
    __shared__ short sA[128][40];
    __shared__ short sB[64][40];
    int tid = threadIdx.x;
    int r0 = blockIdx.x * 128;
    int n0 = blockIdx.y * 64;
    int lane = tid & 63;
    int w = tid >> 6;
    int quad = lane >> 4;
    int lrow = lane & 15;

    f32x4 acc[2][4];
#pragma unroll
    for (int s = 0; s < 2; s++)
#pragma unroll
        for (int t = 0; t < 4; t++) acc[s][t] = (f32x4){0.f, 0.f, 0.f, 0.f};

    for (int k0 = 0; k0 < K; k0 += 32) {
        // stage A: 128x32 shorts, 512 chunks of 16B, 2 per thread
#pragma unroll
        for (int i = 0; i < 2; i++) {
            int c = tid + i * 256;
            int row = c >> 2, col = (c & 3) * 8;
            ushort4 v2[2];
            if (r0 + row < N) {
                const uint4 g = *(const uint4*)(A + (size_t)(r0 + row) * K + k0 + col);
                *(uint4*)v2 = g;
            } else {
                v2[0] = (ushort4){0,0,0,0}; v2[1] = (ushort4){0,0,0,0};
            }
            *(uint4*)&sA[row][col] = *(uint4*)v2;
        }
        // stage B: 64x32 shorts, 256 chunks, 1 per thread
        {
            int row = tid >> 2, col = (tid & 3) * 8;
            const uint4 g = *(const uint4*)(Bt + (size_t)(n0 + row) * K + k0 + col);
            *(uint4*)&sB[row][col] = g;
        }
        __syncthreads();
        short8 afr[2], bfr[4];
#pragma unroll
        for (int s = 0; s < 2; s++)
            afr[s] = *(const short8*)&sA[w * 32 + s * 16 + lrow][quad * 8];
#pragma unroll
        for (int t = 0; t < 4; t++)
            bfr[t] = *(const short8*)&sB[t * 16 + lrow][quad * 8];
#pragma unroll
        for (int s = 0; s < 2; s++)
#pragma unroll
            for (int t = 0; t < 4; t++)
                acc[s][t] = __builtin_amdgcn_mfma_f32_16x16x32_bf16(afr[s], bfr[t], acc[s][t], 0, 0, 0);
        __syncthreads();
    }
    // epilogue
#pragma unroll
    for (int s = 0; s < 2; s++) {
#pragma unroll
        for (int t = 0; t < 4; t++) {
            int col = n0 + t * 16 + lrow;
            float bb = bias[col];
#pragma unroll
            for (int r = 0; r < 4; r++) {
                int row = r0 + w * 32 + s * 16 + quad * 4 + r;
                if (row < N) {
                    float v = acc[s][t][r] + bb;
                    if (RELU_BF16) {
                        ((unsigned short*)outp)[(size_t)row * NOUT + col] = f2bf(fmaxf(v, 0.f));
                    } else {
                        ((float*)outp)[(size_t)row * NOUT + col] = v;
                    }
                }
            }
        }
    }
}

extern "C" void kernel_launch(void* const* d_in, const int* in_sizes, int n_in,
                              void* d_out, int out_size, void* d_ws, size_t ws_size,
                              hipStream_t stream)
{
    const float* x       = (const float*)d_in[0];
    const int*   ei      = (const int*)d_in[1];
    const float* nanchor = (const float*)d_in[2];
    const float* naw     = (const float*)d_in[3];
    const float* nab     = (const float*)d_in[4];
    const float* eanchor = (const float*)d_in[5];
    const float* eww     = (const float*)d_in[6];
    const float* ewb     = (const float*)d_in[7];
    const float* scales  = (const float*)d_in[8];
    const float* w1      = (const float*)d_in[9];
    const float* b1      = (const float*)d_in[10];
    const float* w2      = (const float*)d_in[11];
    const float* b2      = (const float*)d_in[12];

    int N = in_sizes[0] / DD;
    int E = in_sizes[1] / 2;
    float norm = (float)((double)E / (double)N + 1e-6);
    float hin = 0.5f / norm;

    char* wsb = (char*)d_ws;
    size_t off = 0;
    auto alloc = [&](size_t b) -> char* {
        char* p = wsb + off;
        off += (b + 255) & ~(size_t)255;
        return p;
    };
    float* node_x = (float*)alloc((size_t)N * DD * 4);   // becomes z after k_z
    float* yB     = (float*)alloc((size_t)N * DD * 4);
    float* yC     = (float*)alloc((size_t)N * DD * 4);
    float* p1     = (float*)alloc((size_t)N * 8 * 4);
    float* p2     = (float*)alloc((size_t)N * 8 * 4);
    float* coef   = (float*)alloc((size_t)N * 8 * 4);
    unsigned short* comb_bf = (unsigned short*)alloc((size_t)N * 512 * 2);
    unsigned short* h_bf    = (unsigned short*)alloc((size_t)N * 256 * 2);
    unsigned short* w1t     = (unsigned short*)alloc((size_t)512 * 256 * 2);
    unsigned short* w2t     = (unsigned short*)alloc((size_t)256 * 128 * 2);
    int*   deg    = (int*)alloc((size_t)N * 4);
    int*   rowptr = (int*)alloc((size_t)(N + 1) * 4);
    int*   wp     = (int*)alloc((size_t)N * 4);
    int*   adj    = (int*)alloc((size_t)2 * E * 4);

    float* out_final   = (float*)d_out;
    float* out_eprompt = out_final + (size_t)N * DD;

    hipMemsetAsync(coef, 0, (size_t)N * 8 * 4, stream);
    hipMemsetAsync(deg, 0, (size_t)N * 4, stream);

    k_cvtw1<<<(512 * 256 + 255) / 256, 256, 0, stream>>>(w1, scales, w1t);
    k_cvtw2<<<(256 * 128 + 255) / 256, 256, 0, stream>>>(w2, w2t);

    k_node_pre<<<(N + 3) / 4, 256, 0, stream>>>(x, naw, nab, nanchor, eww, node_x, p1, p2, N);
    k_edge<<<(E + 255) / 256, 256, 0, stream>>>(ei, p1, p2, ewb, eanchor, out_eprompt, coef, E);
    k_deg<<<(E + 255) / 256, 256, 0, stream>>>(ei, deg, E);
    k_scan<<<1, 1024, 0, stream>>>(deg, rowptr, wp, N, 2 * E);
    k_fill<<<(E + 255) / 256, 256, 0, stream>>>(ei, wp, adj, E);
    k_z<<<((size_t)N * 32 + 255) / 256, 256, 0, stream>>>(coef, eanchor, node_x, N);

    // 4 chained wavelet steps; bf16 mirror into comb_bf chunks, fp32 chain ping-pong
    k_wav<<<(N + 3) / 4, 128, 0, stream>>>(rowptr, adj, node_x, DD, yB, 1, comb_bf + 0,   hin, N);
    k_wav<<<(N + 3) / 4, 128, 0, stream>>>(rowptr, adj, yB,     DD, yC, 1, comb_bf + 128, hin, N);
    k_wav<<<(N + 3) / 4, 128, 0, stream>>>(rowptr, adj, yC,     DD, yB, 1, comb_bf + 256, hin, N);
    k_wav<<<(N + 3) / 4, 128, 0, stream>>>(rowptr, adj, yB,     DD, yC, 0, comb_bf + 384, hin, N);

    dim3 g1((N + 127) / 128, 4);
    k_gemm<512, true><<<g1, 256, 0, stream>>>(comb_bf, w1t, b1, h_bf, N, 256);
    dim3 g2((N + 127) / 128, 2);
    k_gemm<256, false><<<g2, 256, 0, stream>>>(h_bf, w2t, b2, out_final, N, 128);
}